// Round 13
// baseline (78.373 us; speedup 1.0000x reference)
//
#include <hip/hip_runtime.h>

#define HW    16384
#define CDIM  64
#define BDIM  32
#define NSL   16                 // slices per image (1024 px each)
#define NBLK  (BDIM * NSL)       // 512 blocks
#define NBC   2048
#define SLOTSTRIDE 137           // padded c-stride in dwords

// ws layout:
//   [0)        float acc[2048*16*8]  per (bcKey=c*32+b, slice): {sf,s0,sj,sqj,si,sqi,hi,lo}
//   [1 MB)     float ablk[512*2]     {a1,a2} per block
//   [1 MB+4KB) double gacc[5]        {dis, sf, s0, a1, a2}  (zeroed each launch)
#define OFF_ABLK  (1u << 20)
#define OFF_GACC  ((1u << 20) + 4096u)

__device__ __forceinline__ unsigned ordf(float x) {
    unsigned u = __float_as_uint(x);
    return u ^ ((u >> 31) ? 0xFFFFFFFFu : 0x80000000u);  // strictly monotone
}

template<int CTRL>
__device__ __forceinline__ float dpp_addstep(float x) {
    int m = __builtin_amdgcn_update_dpp(0, __float_as_int(x), CTRL, 0xf, 0xf, true);
    return x + __int_as_float(m);
}
// 16-lane suffix-sum; lane 15/31/47/63 holds its row total
__device__ __forceinline__ float red16(float x) {
    x = dpp_addstep<0x111>(x); x = dpp_addstep<0x112>(x);
    x = dpp_addstep<0x114>(x); x = dpp_addstep<0x118>(x);
    return x;
}
template<int CTRL>
__device__ __forceinline__ void dpp_lexstep(unsigned& hi, unsigned& lo) {
    unsigned nh = (unsigned)__builtin_amdgcn_update_dpp(0, (int)hi, CTRL, 0xf, 0xf, true);
    unsigned nl = (unsigned)__builtin_amdgcn_update_dpp(0, (int)lo, CTRL, 0xf, 0xf, true);
    bool take = (nh > hi) || (nh == hi && nl > lo);
    hi = take ? nh : hi; lo = take ? nl : lo;
}
__device__ __forceinline__ void lexmax16(unsigned& hi, unsigned& lo) {
    dpp_lexstep<0x111>(hi, lo); dpp_lexstep<0x112>(hi, lo);
    dpp_lexstep<0x114>(hi, lo); dpp_lexstep<0x118>(hi, lo);
}

// per-channel body: macro (no lambda -> no SROA blocker, everything in regs)
#define PROC(V, C) do {                                                          \
    float x0 = (V).x, x1 = (V).y, x2 = (V).z, x3 = (V).w;                        \
    m2x = __builtin_amdgcn_fmed3f(x0, m1x, m2x); m1x = fmaxf(m1x, x0); s2x = fmaf(x0, x0, s2x); \
    m2y = __builtin_amdgcn_fmed3f(x1, m1y, m2y); m1y = fmaxf(m1y, x1); s2y = fmaf(x1, x1, s2y); \
    m2z = __builtin_amdgcn_fmed3f(x2, m1z, m2z); m1z = fmaxf(m1z, x2); s2z = fmaf(x2, x2, s2z); \
    m2w = __builtin_amdgcn_fmed3f(x3, m1w, m2w); m1w = fmaxf(m1w, x3); s2w = fmaf(x3, x3, s2w); \
    float q0 = x0*x0, q1 = x1*x1, q2 = x2*x2, q3 = x3*x3;                        \
    float sf = (x0 + x1) + (x2 + x3);                                            \
    float s0 = (q0 + q1) + (q2 + q3);                                            \
    float sj  = fmaf(q3, fj3, fmaf(q2, fj2, fmaf(q1, fj1, q0 * fj0)));           \
    float sqj = fmaf(q3, fq3, fmaf(q2, fq2, fmaf(q1, fq1, q0 * fq0)));           \
    float bm = x0; int bj = 0;                                                   \
    if (x1 > bm) { bm = x1; bj = 1; }                                            \
    if (x2 > bm) { bm = x2; bj = 2; }                                            \
    if (x3 > bm) { bm = x3; bj = 3; }                                            \
    unsigned hi = ordf(bm), lo = 16383u - (unsigned)(px0 + bj);                  \
    sf = red16(sf); s0 = red16(s0); sj = red16(sj); sqj = red16(sqj);            \
    lexmax16(hi, lo);                                                            \
    if (tail) {                                                                  \
        float* sp = &slots[(C) * SLOTSTRIDE + rowslot * 8];                      \
        sp[0] = sf; sp[1] = s0; sp[2] = sj; sp[3] = sqj;                         \
        sp[4] = fi * s0; sp[5] = fi2 * s0;                                       \
        sp[6] = __uint_as_float(hi); sp[7] = __uint_as_float(lo);                \
    }                                                                            \
} while (0)

#define PROC16(BUF, CB) do {                                                     \
    PROC(BUF[0],  (CB)+0);  PROC(BUF[1],  (CB)+1);  PROC(BUF[2],  (CB)+2);       \
    PROC(BUF[3],  (CB)+3);  PROC(BUF[4],  (CB)+4);  PROC(BUF[5],  (CB)+5);       \
    PROC(BUF[6],  (CB)+6);  PROC(BUF[7],  (CB)+7);  PROC(BUF[8],  (CB)+8);       \
    PROC(BUF[9],  (CB)+9);  PROC(BUF[10], (CB)+10); PROC(BUF[11], (CB)+11);      \
    PROC(BUF[12], (CB)+12); PROC(BUF[13], (CB)+13); PROC(BUF[14], (CB)+14);      \
    PROC(BUF[15], (CB)+15);                                                      \
} while (0)

// Single pass. Block = (b, slice of 1024 px); thread owns 4 consecutive px.
// Pixel-direction top2+S2 in registers; channel-direction reduced across
// 16-lane rows via DPP, lane 15 writes an 8-dword LDS slot per channel.
__global__ __launch_bounds__(256, 2) void f_onepass(const float* __restrict__ feat,
                                                    float* __restrict__ acc,
                                                    float* __restrict__ ablk) {
    __shared__ float slots[CDIM * SLOTSTRIDE];   // ~35 KB
    __shared__ float ared[32];

    const int t   = threadIdx.x;
    const int blk = blockIdx.x;
    const int b   = blk >> 4, sl = blk & 15;
    const int px0 = sl * 1024 + t * 4;           // 4 px, same image row
    const float fi  = (float)(px0 >> 7);         // uniform within 16-lane group
    const float fi2 = fi * fi;
    const float fj0 = (float)(px0 & 127);
    const float fj1 = fj0 + 1.f, fj2 = fj0 + 2.f, fj3 = fj0 + 3.f;
    const float fq0 = fj0*fj0, fq1 = fj1*fj1, fq2 = fj2*fj2, fq3 = fj3*fj3;
    const int  rowslot = t >> 4;
    const bool tail    = ((t & 15) == 15);
    const float* src = feat + (size_t)b * (CDIM * HW) + px0;

    float m1x=-INFINITY, m1y=-INFINITY, m1z=-INFINITY, m1w=-INFINITY;
    float m2x=-INFINITY, m2y=-INFINITY, m2z=-INFINITY, m2w=-INFINITY;
    float s2x=0.f, s2y=0.f, s2z=0.f, s2w=0.f;

    float4 A[16], B[16];
    #pragma unroll
    for (int k = 0; k < 16; ++k) A[k] = *(const float4*)(src + (size_t)k * HW);
    #pragma unroll
    for (int k = 0; k < 16; ++k) B[k] = *(const float4*)(src + (size_t)(k + 16) * HW);
    __builtin_amdgcn_sched_barrier(0);

    #pragma unroll 1
    for (int c0 = 0; c0 < 64; c0 += 32) {
        PROC16(A, c0);
        if (c0 < 32) {
            #pragma unroll
            for (int k = 0; k < 16; ++k) A[k] = *(const float4*)(src + (size_t)(32 + k) * HW);
            __builtin_amdgcn_sched_barrier(0);
        }
        PROC16(B, c0 + 16);
        if (c0 < 32) {
            #pragma unroll
            for (int k = 0; k < 16; ++k) B[k] = *(const float4*)(src + (size_t)(48 + k) * HW);
            __builtin_amdgcn_sched_barrier(0);
        }
    }

    // pixel-direction closed form per owned pixel, 16-lane reduce
    float a1, a2;
    {
        float qx = m1x*m1x, qy = m1y*m1y, qz = m1z*m1z, qw = m1w*m1w;
        float rx = s2x - qx, ry = s2y - qy, rz = s2z - qz, rw = s2w - qw;
        a1 = qx*rx + m2x*m2x*qx + qy*ry + m2y*m2y*qy
           + qz*rz + m2z*m2z*qz + qw*rw + m2w*m2w*qw;
        a2 = m1x*rx + m2x*qx + m1y*ry + m2y*qy
           + m1z*rz + m2z*qz + m1w*rw + m2w*qw;
    }
    a1 = red16(a1); a2 = red16(a2);
    if (tail) { ared[rowslot * 2] = a1; ared[rowslot * 2 + 1] = a2; }
    __syncthreads();   // only barrier

    if (t < 64) {      // combine 16 row-slots for channel c = t
        const int c = t;
        float SF = 0, S0 = 0, SJ = 0, SQJ = 0, SI = 0, SQI = 0;
        unsigned HI = 0, LO = 0;
        #pragma unroll
        for (int rs = 0; rs < 16; ++rs) {
            const float* sp = &slots[c * SLOTSTRIDE + rs * 8];
            SF += sp[0]; S0 += sp[1]; SJ += sp[2]; SQJ += sp[3];
            SI += sp[4]; SQI += sp[5];
            unsigned nh = __float_as_uint(sp[6]), nl = __float_as_uint(sp[7]);
            bool take = (nh > HI) || (nh == HI && nl > LO);
            HI = take ? nh : HI; LO = take ? nl : LO;
        }
        float* g = &acc[(((size_t)c * 32 + b) * 16 + sl) * 8];
        g[0] = SF; g[1] = S0; g[2] = SJ; g[3] = SQJ; g[4] = SI; g[5] = SQI;
        g[6] = __uint_as_float(HI); g[7] = __uint_as_float(LO);
    } else if (t == 255) {
        float A1 = 0, A2 = 0;
        #pragma unroll
        for (int rs = 0; rs < 16; ++rs) { A1 += ared[rs * 2]; A2 += ared[rs * 2 + 1]; }
        ablk[blk * 2] = A1; ablk[blk * 2 + 1] = A2;
    }
}

// 32 blocks; block handles 64 bcKeys. Thread t: bc_local = t>>2, 4 slices each.
// Per-block LDS reduce then 3 (+2 on block 0) double atomics.
__global__ __launch_bounds__(256) void k4_partial(const float* __restrict__ acc,
                                                  const float* __restrict__ ablk,
                                                  double* __restrict__ gacc) {
    const int t = threadIdx.x;
    const int bc = blockIdx.x * 64 + (t >> 2);
    const int sg = t & 3;

    float SF = 0, S0 = 0, SJ = 0, SQJ = 0, SI = 0, SQI = 0;
    unsigned HI = 0, LO = 0;
    #pragma unroll
    for (int s = 0; s < 4; ++s) {
        const float* g = &acc[(((size_t)bc) * 16 + sg * 4 + s) * 8];
        SF += g[0]; S0 += g[1]; SJ += g[2]; SQJ += g[3];
        SI += g[4]; SQI += g[5];
        unsigned nh = __float_as_uint(g[6]), nl = __float_as_uint(g[7]);
        bool take = (nh > HI) || (nh == HI && nl > LO);
        HI = take ? nh : HI; LO = take ? nl : LO;
    }
    // reduce across the 4 lanes of this bc
    #pragma unroll
    for (int off = 1; off < 4; off <<= 1) {
        SF  += __shfl_down(SF,  off, 4);
        S0  += __shfl_down(S0,  off, 4);
        SJ  += __shfl_down(SJ,  off, 4);
        SQJ += __shfl_down(SQJ, off, 4);
        SI  += __shfl_down(SI,  off, 4);
        SQI += __shfl_down(SQI, off, 4);
        unsigned nh = __shfl_down(HI, off, 4), nl = __shfl_down(LO, off, 4);
        bool take = (nh > HI) || (nh == HI && nl > LO);
        HI = take ? nh : HI; LO = take ? nl : LO;
    }

    __shared__ double rd[64], rf[64], r0[64];
    if (sg == 0) {
        int p = 16383 - (int)LO;
        double mi = (double)(p >> 7), mj = (double)(p & 127);
        double dS0 = (double)S0;
        rd[t >> 2] = (mi*mi + mj*mj) * dS0 + ((double)SQI + (double)SQJ)
                   - 2.0 * (mi * (double)SI + mj * (double)SJ);
        rf[t >> 2] = (double)SF;
        r0[t >> 2] = dS0;
    }
    __syncthreads();
    for (int off = 32; off > 0; off >>= 1) {
        if (t < off) { rd[t] += rd[t + off]; rf[t] += rf[t + off]; r0[t] += r0[t + off]; }
        __syncthreads();
    }
    if (t == 0) {
        atomicAdd(&gacc[0], rd[0]);
        atomicAdd(&gacc[1], rf[0]);
        atomicAdd(&gacc[2], r0[0]);
    }

    if (blockIdx.x == 0) {   // fold ablk
        float a1 = 0, a2 = 0;
        for (int i = t; i < NBLK; i += 256) { a1 += ablk[i * 2]; a2 += ablk[i * 2 + 1]; }
        __shared__ float s1[256], s2a[256];
        s1[t] = a1; s2a[t] = a2;
        __syncthreads();
        for (int off = 128; off > 0; off >>= 1) {
            if (t < off) { s1[t] += s1[t + off]; s2a[t] += s2a[t + off]; }
            __syncthreads();
        }
        if (t == 0) {
            atomicAdd(&gacc[3], (double)s1[0]);
            atomicAdd(&gacc[4], (double)s2a[0]);
        }
    }
}

__global__ void k5_final(const double* __restrict__ gacc, float* __restrict__ out) {
    const double n = 33554432.0;   // 32*64*128*128
    double mgr = gacc[1] / n;
    out[0] = (float)(gacc[0] / n);
    out[1] = (float)((gacc[3] - 2.0 * mgr * gacc[4] + mgr * mgr * gacc[2]) / n);
}

extern "C" void kernel_launch(void* const* d_in, const int* in_sizes, int n_in,
                              void* d_out, int out_size, void* d_ws, size_t ws_size,
                              hipStream_t stream) {
    const float* feat = (const float*)d_in[0];
    float* out = (float*)d_out;
    char* ws = (char*)d_ws;

    float*  acc  = (float*)ws;
    float*  ablk = (float*)(ws + OFF_ABLK);
    double* gacc = (double*)(ws + OFF_GACC);

    hipMemsetAsync(gacc, 0, 5 * sizeof(double), stream);
    f_onepass<<<NBLK, 256, 0, stream>>>(feat, acc, ablk);
    k4_partial<<<32, 256, 0, stream>>>(acc, ablk, gacc);
    k5_final<<<1, 1, 0, stream>>>(gacc, out);
}

// Round 14
// 55.426 us; speedup vs baseline: 1.4140x; 1.4140x over previous
//
#include <hip/hip_runtime.h>

#define HW    16384
#define CDIM  64
#define BDIM  32
#define NSL   16                 // slices per image (1024 px each)
#define NBLK  (BDIM * NSL)       // 512 blocks
#define NBC   2048
#define SLOTSTRIDE 137           // padded c-stride in dwords

// ws layout:
//   [0)        float acc[2048*16*8]  per (bcKey=c*32+b, slice): {s0,sj,sqj,si,sqi,hi,lo,-}
//   [1 MB)     float ablk[512*3]     {a1,a2,sf} per block
//   [1 MB+8KB) double gacc[5]        {dis, sf, s0, a1, a2}  (zeroed each launch)
#define OFF_ABLK  (1u << 20)
#define OFF_GACC  ((1u << 20) + 8192u)

__device__ __forceinline__ unsigned ordf(float x) {
    unsigned u = __float_as_uint(x);
    return u ^ ((u >> 31) ? 0xFFFFFFFFu : 0x80000000u);  // strictly monotone
}

template<int CTRL>
__device__ __forceinline__ float dpp_addstep(float x) {
    int m = __builtin_amdgcn_update_dpp(0, __float_as_int(x), CTRL, 0xf, 0xf, true);
    return x + __int_as_float(m);
}
// 16-lane suffix-sum; lanes 15/31/47/63 hold their row totals
__device__ __forceinline__ float red16(float x) {
    x = dpp_addstep<0x111>(x); x = dpp_addstep<0x112>(x);
    x = dpp_addstep<0x114>(x); x = dpp_addstep<0x118>(x);
    return x;
}
template<int CTRL>
__device__ __forceinline__ void dpp_lexstep(unsigned& hi, unsigned& lo) {
    unsigned nh = (unsigned)__builtin_amdgcn_update_dpp(0, (int)hi, CTRL, 0xf, 0xf, true);
    unsigned nl = (unsigned)__builtin_amdgcn_update_dpp(0, (int)lo, CTRL, 0xf, 0xf, true);
    bool take = (nh > hi) || (nh == hi && nl > lo);
    hi = take ? nh : hi; lo = take ? nl : lo;
}
__device__ __forceinline__ void lexmax16(unsigned& hi, unsigned& lo) {
    dpp_lexstep<0x111>(hi, lo); dpp_lexstep<0x112>(hi, lo);
    dpp_lexstep<0x114>(hi, lo); dpp_lexstep<0x118>(hi, lo);
}

// per-channel body: macro over named scalars (no lambda, no runtime-indexed
// arrays -> everything stays in registers; rule #20)
#define PROC(V, C) do {                                                          \
    float x0 = (V).x, x1 = (V).y, x2 = (V).z, x3 = (V).w;                        \
    m2x = __builtin_amdgcn_fmed3f(x0, m1x, m2x); m1x = fmaxf(m1x, x0); s2x = fmaf(x0, x0, s2x); \
    m2y = __builtin_amdgcn_fmed3f(x1, m1y, m2y); m1y = fmaxf(m1y, x1); s2y = fmaf(x1, x1, s2y); \
    m2z = __builtin_amdgcn_fmed3f(x2, m1z, m2z); m1z = fmaxf(m1z, x2); s2z = fmaf(x2, x2, s2z); \
    m2w = __builtin_amdgcn_fmed3f(x3, m1w, m2w); m1w = fmaxf(m1w, x3); s2w = fmaf(x3, x3, s2w); \
    float q0 = x0*x0, q1 = x1*x1, q2 = x2*x2, q3 = x3*x3;                        \
    sfall += (x0 + x1) + (x2 + x3);                                              \
    float s0 = (q0 + q1) + (q2 + q3);                                            \
    float sj  = fmaf(q3, fj3, fmaf(q2, fj2, fmaf(q1, fj1, q0 * fj0)));           \
    float sqj = fmaf(q3, fq3, fmaf(q2, fq2, fmaf(q1, fq1, q0 * fq0)));           \
    float bm = x0; int bj = 0;                                                   \
    if (x1 > bm) { bm = x1; bj = 1; }                                            \
    if (x2 > bm) { bm = x2; bj = 2; }                                            \
    if (x3 > bm) { bm = x3; bj = 3; }                                            \
    unsigned hi = ordf(bm), lo = 16383u - (unsigned)(px0 + bj);                  \
    s0 = red16(s0); sj = red16(sj); sqj = red16(sqj);                            \
    lexmax16(hi, lo);                                                            \
    if (tail) {                                                                  \
        float* sp = &slots[(C) * SLOTSTRIDE + rowslot * 8];                      \
        sp[0] = s0; sp[1] = sj; sp[2] = sqj;                                     \
        sp[3] = fi * s0; sp[4] = fi2 * s0;                                       \
        sp[5] = __uint_as_float(hi); sp[6] = __uint_as_float(lo);                \
    }                                                                            \
} while (0)

#define PROC8(BUF, CB) do {                                                      \
    PROC(BUF[0], (CB)+0); PROC(BUF[1], (CB)+1); PROC(BUF[2], (CB)+2);            \
    PROC(BUF[3], (CB)+3); PROC(BUF[4], (CB)+4); PROC(BUF[5], (CB)+5);            \
    PROC(BUF[6], (CB)+6); PROC(BUF[7], (CB)+7);                                  \
} while (0)

// Single pass. Block = (b, slice of 1024 px); thread owns 4 consecutive px.
// Pixel-direction top2+S2 in registers; channel-direction reduced across
// 16-lane rows via DPP, lane 15 writes a 7-dword LDS slot per channel.
// A/B ping-pong (8 float4 each = 64 buffer VGPRs) pinned by sched_barrier.
__global__ __launch_bounds__(256, 2) void f_onepass(const float* __restrict__ feat,
                                                    float* __restrict__ acc,
                                                    float* __restrict__ ablk) {
    __shared__ float slots[CDIM * SLOTSTRIDE];   // ~35 KB
    __shared__ float ared[48];

    const int t   = threadIdx.x;
    const int blk = blockIdx.x;
    const int b   = blk >> 4, sl = blk & 15;
    const int px0 = sl * 1024 + t * 4;           // 4 px, within one image row
    const float fi  = (float)(px0 >> 7);         // uniform within 16-lane group
    const float fi2 = fi * fi;
    const float fj0 = (float)(px0 & 127);
    const float fj1 = fj0 + 1.f, fj2 = fj0 + 2.f, fj3 = fj0 + 3.f;
    const float fq0 = fj0*fj0, fq1 = fj1*fj1, fq2 = fj2*fj2, fq3 = fj3*fj3;
    const int  rowslot = t >> 4;
    const bool tail    = ((t & 15) == 15);
    const float* src = feat + (size_t)b * (CDIM * HW) + px0;

    float m1x=-INFINITY, m1y=-INFINITY, m1z=-INFINITY, m1w=-INFINITY;
    float m2x=-INFINITY, m2y=-INFINITY, m2z=-INFINITY, m2w=-INFINITY;
    float s2x=0.f, s2y=0.f, s2z=0.f, s2w=0.f;
    float sfall = 0.f;

    float4 A[8], B[8];
    #pragma unroll
    for (int k = 0; k < 8; ++k) A[k] = *(const float4*)(src + (size_t)k * HW);
    #pragma unroll
    for (int k = 0; k < 8; ++k) B[k] = *(const float4*)(src + (size_t)(k + 8) * HW);
    __builtin_amdgcn_sched_barrier(0);

    #pragma unroll 1
    for (int c0 = 0; c0 < 64; c0 += 16) {
        PROC8(A, c0);
        if (c0 < 48) {
            #pragma unroll
            for (int k = 0; k < 8; ++k) A[k] = *(const float4*)(src + (size_t)(c0 + 16 + k) * HW);
            __builtin_amdgcn_sched_barrier(0);
        }
        PROC8(B, c0 + 8);
        if (c0 < 48) {
            #pragma unroll
            for (int k = 0; k < 8; ++k) B[k] = *(const float4*)(src + (size_t)(c0 + 24 + k) * HW);
            __builtin_amdgcn_sched_barrier(0);
        }
    }

    // pixel-direction closed form per owned pixel, 16-lane reduce
    float a1, a2;
    {
        float qx = m1x*m1x, qy = m1y*m1y, qz = m1z*m1z, qw = m1w*m1w;
        float rx = s2x - qx, ry = s2y - qy, rz = s2z - qz, rw = s2w - qw;
        a1 = qx*rx + m2x*m2x*qx + qy*ry + m2y*m2y*qy
           + qz*rz + m2z*m2z*qz + qw*rw + m2w*m2w*qw;
        a2 = m1x*rx + m2x*qx + m1y*ry + m2y*qy
           + m1z*rz + m2z*qz + m1w*rw + m2w*qw;
    }
    a1 = red16(a1); a2 = red16(a2); sfall = red16(sfall);
    if (tail) {
        ared[rowslot * 3]     = a1;
        ared[rowslot * 3 + 1] = a2;
        ared[rowslot * 3 + 2] = sfall;
    }
    __syncthreads();   // only barrier

    if (t < 64) {      // combine 16 row-slots for channel c = t
        const int c = t;
        float S0 = 0, SJ = 0, SQJ = 0, SI = 0, SQI = 0;
        unsigned HI = 0, LO = 0;
        #pragma unroll
        for (int rs = 0; rs < 16; ++rs) {
            const float* sp = &slots[c * SLOTSTRIDE + rs * 8];
            S0 += sp[0]; SJ += sp[1]; SQJ += sp[2];
            SI += sp[3]; SQI += sp[4];
            unsigned nh = __float_as_uint(sp[5]), nl = __float_as_uint(sp[6]);
            bool take = (nh > HI) || (nh == HI && nl > LO);
            HI = take ? nh : HI; LO = take ? nl : LO;
        }
        float* g = &acc[(((size_t)c * 32 + b) * 16 + sl) * 8];
        g[0] = S0; g[1] = SJ; g[2] = SQJ; g[3] = SI; g[4] = SQI;
        g[5] = __uint_as_float(HI); g[6] = __uint_as_float(LO);
    } else if (t == 255) {
        float A1 = 0, A2 = 0, SFB = 0;
        #pragma unroll
        for (int rs = 0; rs < 16; ++rs) {
            A1 += ared[rs * 3]; A2 += ared[rs * 3 + 1]; SFB += ared[rs * 3 + 2];
        }
        ablk[blk * 3] = A1; ablk[blk * 3 + 1] = A2; ablk[blk * 3 + 2] = SFB;
    }
}

// 32 blocks; block handles 64 bcKeys. Thread t: bc = blk*64 + (t>>2), 4 slices each.
__global__ __launch_bounds__(256) void k4_partial(const float* __restrict__ acc,
                                                  const float* __restrict__ ablk,
                                                  double* __restrict__ gacc) {
    const int t = threadIdx.x;
    const int bc = blockIdx.x * 64 + (t >> 2);
    const int sg = t & 3;

    float S0 = 0, SJ = 0, SQJ = 0, SI = 0, SQI = 0;
    unsigned HI = 0, LO = 0;
    #pragma unroll
    for (int s = 0; s < 4; ++s) {
        const float* g = &acc[(((size_t)bc) * 16 + sg * 4 + s) * 8];
        S0 += g[0]; SJ += g[1]; SQJ += g[2]; SI += g[3]; SQI += g[4];
        unsigned nh = __float_as_uint(g[5]), nl = __float_as_uint(g[6]);
        bool take = (nh > HI) || (nh == HI && nl > LO);
        HI = take ? nh : HI; LO = take ? nl : LO;
    }
    #pragma unroll
    for (int off = 1; off < 4; off <<= 1) {
        S0  += __shfl_down(S0,  off, 4);
        SJ  += __shfl_down(SJ,  off, 4);
        SQJ += __shfl_down(SQJ, off, 4);
        SI  += __shfl_down(SI,  off, 4);
        SQI += __shfl_down(SQI, off, 4);
        unsigned nh = __shfl_down(HI, off, 4), nl = __shfl_down(LO, off, 4);
        bool take = (nh > HI) || (nh == HI && nl > LO);
        HI = take ? nh : HI; LO = take ? nl : LO;
    }

    __shared__ double rd[64], r0[64];
    if (sg == 0) {
        int p = 16383 - (int)LO;
        double mi = (double)(p >> 7), mj = (double)(p & 127);
        double dS0 = (double)S0;
        rd[t >> 2] = (mi*mi + mj*mj) * dS0 + ((double)SQI + (double)SQJ)
                   - 2.0 * (mi * (double)SI + mj * (double)SJ);
        r0[t >> 2] = dS0;
    }
    __syncthreads();
    for (int off = 32; off > 0; off >>= 1) {
        if (t < off) { rd[t] += rd[t + off]; r0[t] += r0[t + off]; }
        __syncthreads();
    }
    if (t == 0) {
        atomicAdd(&gacc[0], rd[0]);
        atomicAdd(&gacc[2], r0[0]);
    }

    if (blockIdx.x == 0) {   // fold ablk: a1, a2, global sum f
        float a1 = 0, a2 = 0, sf = 0;
        for (int i = t; i < NBLK; i += 256) {
            a1 += ablk[i * 3]; a2 += ablk[i * 3 + 1]; sf += ablk[i * 3 + 2];
        }
        __shared__ float s1[256], s2a[256], s3[256];
        s1[t] = a1; s2a[t] = a2; s3[t] = sf;
        __syncthreads();
        for (int off = 128; off > 0; off >>= 1) {
            if (t < off) { s1[t] += s1[t + off]; s2a[t] += s2a[t + off]; s3[t] += s3[t + off]; }
            __syncthreads();
        }
        if (t == 0) {
            atomicAdd(&gacc[3], (double)s1[0]);
            atomicAdd(&gacc[4], (double)s2a[0]);
            atomicAdd(&gacc[1], (double)s3[0]);
        }
    }
}

__global__ void k5_final(const double* __restrict__ gacc, float* __restrict__ out) {
    const double n = 33554432.0;   // 32*64*128*128
    double mgr = gacc[1] / n;
    out[0] = (float)(gacc[0] / n);
    out[1] = (float)((gacc[3] - 2.0 * mgr * gacc[4] + mgr * mgr * gacc[2]) / n);
}

extern "C" void kernel_launch(void* const* d_in, const int* in_sizes, int n_in,
                              void* d_out, int out_size, void* d_ws, size_t ws_size,
                              hipStream_t stream) {
    const float* feat = (const float*)d_in[0];
    float* out = (float*)d_out;
    char* ws = (char*)d_ws;

    float*  acc  = (float*)ws;
    float*  ablk = (float*)(ws + OFF_ABLK);
    double* gacc = (double*)(ws + OFF_GACC);

    hipMemsetAsync(gacc, 0, 5 * sizeof(double), stream);
    f_onepass<<<NBLK, 256, 0, stream>>>(feat, acc, ablk);
    k4_partial<<<32, 256, 0, stream>>>(acc, ablk, gacc);
    k5_final<<<1, 1, 0, stream>>>(gacc, out);
}